// Round 9
// baseline (469.819 us; speedup 1.0000x reference)
//
#include <hip/hip_runtime.h>
#include <hip/hip_bf16.h>

#define H0 480
#define W0 640
#define H1 240
#define W1 320
#define H2 120
#define W2 160
#define H3 60
#define W3 80

// fp32 weight buffer offsets (in floats) inside d_ws  (transposed pointwise copies)
#define W_PW1T  0      // 5*32  [cin*32+o]
#define W_PW2T  160    // 32*64 [cin*64+o]
#define W_PW3T  2208   // 64*64 [cin*64+o]
#define WBUF_BYTES 65536

#define F2_PB (64 * H2 * W2)   // 1,228,800
#define F3_PB (64 * H3 * W3)   //   307,200

// ---------------- K0: transpose pointwise weights ---------------------------
__global__ __launch_bounds__(256) void k_cvt(
    const float* __restrict__ pw1, const float* __restrict__ pw2,
    const float* __restrict__ pw3, float* __restrict__ wb)
{
    int t = threadIdx.x;
    for (int i = t; i < 160;  i += 256) { int o = i / 5,  c = i % 5;  wb[W_PW1T + c*32 + o] = pw1[i]; }
    for (int i = t; i < 2048; i += 256) { int o = i >> 5, c = i & 31; wb[W_PW2T + c*64 + o] = pw2[i]; }
    for (int i = t; i < 4096; i += 256) { int o = i >> 6, c = i & 63; wb[W_PW3T + c*64 + o] = pw3[i]; }
}

// ---------------- K12: fused stage1+stage2, register-direct ------------------
// 1 thread per f2 pixel. Flow taps: 1 scalar + 1 aligned-float2 per window row
// (iw0 odd -> iw0+1 is 8B aligned). pw2 rank-1 update on float2 acc pairs.
__global__ __launch_bounds__(256, 3) void k_fuse12(
    const float* __restrict__ flow, const float* __restrict__ dw1,
    const float* __restrict__ b1, const float* __restrict__ dw2,
    const float* __restrict__ b2, const float* __restrict__ wb,
    float* __restrict__ out)
{
    int idx = blockIdx.x * 256 + threadIdx.x;     // 614,400 exact
    int ow = idx % W2; int tmp = idx / W2; int oh = tmp % H2; int b = tmp / H2;

    int fh0 = 2*oh - 1, fw0 = 2*ow - 1;
    const float sy = 2.f / (H0 - 1), sx = 2.f / (W0 - 1);

    float d[9][5];
    float vm[9];

    #pragma unroll
    for (int r = 0; r < 3; r++) {
        #pragma unroll
        for (int s = 0; s < 3; s++) {
            int p = r*3 + s;
            int fh = fh0 + r, fw = fw0 + s;
            vm[p] = (fh >= 0 && fw >= 0) ? 1.f : 0.f;   // f1 zero-pad mask
            int fhc = fh < 0 ? 0 : fh, fwc = fw < 0 ? 0 : fw;
            int ih0 = 2*fhc - 1, iw0 = 2*fwc - 1;       // iw0 odd or -1
            float mh0 = ih0 >= 0 ? 1.f : 0.f;
            float mw0 = iw0 >= 0 ? 1.f : 0.f;
            int ihw[3] = { ih0 < 0 ? 0 : ih0, ih0 + 1, ih0 + 2 };
            int iwc = iw0 < 0 ? 0 : iw0;

            // flow channels via vector row loads
            #pragma unroll
            for (int c = 0; c < 2; c++) {
                const float* base = flow + ((size_t)(b*2 + c)) * (H0*W0);
                const float* w9 = dw1 + c*9;
                float a = 0.f;
                #pragma unroll
                for (int ky = 0; ky < 3; ky++) {
                    const float* rp = base + (size_t)ihw[ky] * W0;
                    float  t0  = rp[iwc];
                    float2 t12 = *(const float2*)(rp + iw0 + 1);   // 8B aligned
                    float rowv = w9[ky*3 + 0] * (mw0 * t0);
                    rowv = fmaf(w9[ky*3 + 1], t12.x, rowv);
                    rowv = fmaf(w9[ky*3 + 2], t12.y, rowv);
                    a = (ky == 0) ? fmaf(mh0, rowv, a) : (a + rowv);
                }
                d[p][c] = a;
            }
            // coordinate channels x, y, r^2
            {
                float mh[3] = { mh0, 1.f, 1.f };
                float mw[3] = { mw0, 1.f, 1.f };
                float ax = 0.f, ay = 0.f, ar = 0.f;
                #pragma unroll
                for (int ky = 0; ky < 3; ky++) {
                    float yv = fmaf((float)(ih0 + ky), sy, -1.f);
                    #pragma unroll
                    for (int kx = 0; kx < 3; kx++) {
                        float xv = fmaf((float)(iw0 + kx), sx, -1.f);
                        float m = mh[ky] * mw[kx];
                        ax = fmaf(dw1[18 + ky*3 + kx], m * xv, ax);
                        ay = fmaf(dw1[27 + ky*3 + kx], m * yv, ay);
                        ar = fmaf(dw1[36 + ky*3 + kx], m * (xv*xv + yv*yv), ar);
                    }
                }
                d[p][2] = ax; d[p][3] = ay; d[p][4] = ar;
            }
        }
    }

    float2 acc[32];
    const float2* b22 = (const float2*)b2;
    #pragma unroll
    for (int o = 0; o < 32; o++) acc[o] = b22[o];

    for (int c = 0; c < 32; c++) {
        const float* w1 = wb + W_PW1T + c;     // uniform
        float w10 = w1[0], w11 = w1[32], w12 = w1[64], w13 = w1[96], w14 = w1[128];
        float bc = b1[c];
        const float* w9 = dw2 + c*9;           // uniform
        float dv = 0.f;
        #pragma unroll
        for (int p = 0; p < 9; p++) {
            float v = bc;
            v = fmaf(w10, d[p][0], v);
            v = fmaf(w11, d[p][1], v);
            v = fmaf(w12, d[p][2], v);
            v = fmaf(w13, d[p][3], v);
            v = fmaf(w14, d[p][4], v);
            float f1v = v > 0.f ? v : (__expf(v) - 1.f);
            dv = fmaf(w9[p], f1v * vm[p], dv);
        }
        const float2* wr = (const float2*)(wb + W_PW2T + c*64);   // uniform
        #pragma unroll
        for (int o = 0; o < 32; o++) {
            acc[o].x = fmaf(wr[o].x, dv, acc[o].x);
            acc[o].y = fmaf(wr[o].y, dv, acc[o].y);
        }
    }

    size_t obase = ((size_t)b * 64) * (H2*W2) + (size_t)oh*W2 + ow;
    #pragma unroll
    for (int o = 0; o < 32; o++) {
        float vx = acc[o].x, vy = acc[o].y;
        out[obase + (size_t)(2*o  )*(H2*W2)] = vx > 0.f ? vx : (__expf(vx) - 1.f);
        out[obase + (size_t)(2*o+1)*(H2*W2)] = vy > 0.f ? vy : (__expf(vy) - 1.f);
    }
}

// ---------------- K3: dwsep3 + ELU, register-direct, oc-half split -----------
// thread = (f3 px, oc-half); 1200 blocks x 256. Row taps: scalar + float2.
__global__ __launch_bounds__(256, 6) void k_stage3(
    const float* __restrict__ in, const float* __restrict__ dw3,
    const float* __restrict__ b3, const float* __restrict__ wb,
    float* __restrict__ out)
{
    int t = threadIdx.x;
    int px = blockIdx.x * 128 + (t & 127);        // 153,600 exact
    int half = t >> 7;                            // wave-uniform
    int ow = px % W3; int tmp = px / W3; int oh = tmp % H3; int b = tmp / H3;
    int ih0 = 2*oh - 1, iw0 = 2*ow - 1;           // iw0 odd or -1
    float mh0 = ih0 >= 0 ? 1.f : 0.f;
    float mw0 = iw0 >= 0 ? 1.f : 0.f;
    int ihw[3] = { ih0 < 0 ? 0 : ih0, ih0 + 1, ih0 + 2 };
    int iwc = iw0 < 0 ? 0 : iw0;

    float2 acc[16];
    const float2* b32 = (const float2*)(b3 + half*32);
    #pragma unroll
    for (int o = 0; o < 16; o++) acc[o] = b32[o];

    const float* inb = in + (size_t)b * F2_PB;
    for (int c = 0; c < 64; c++) {
        const float* g = inb + (size_t)c * (H2*W2);
        const float* w9 = dw3 + c*9;              // uniform
        float dv = 0.f;
        #pragma unroll
        for (int ky = 0; ky < 3; ky++) {
            const float* rp = g + (size_t)ihw[ky] * W2;
            float  t0  = rp[iwc];
            float2 t12 = *(const float2*)(rp + iw0 + 1);   // 8B aligned
            float rowv = w9[ky*3 + 0] * (mw0 * t0);
            rowv = fmaf(w9[ky*3 + 1], t12.x, rowv);
            rowv = fmaf(w9[ky*3 + 2], t12.y, rowv);
            dv = (ky == 0) ? fmaf(mh0, rowv, dv) : (dv + rowv);
        }
        const float2* wr = (const float2*)(wb + W_PW3T + c*64 + half*32);  // uniform
        #pragma unroll
        for (int o = 0; o < 16; o++) {
            acc[o].x = fmaf(wr[o].x, dv, acc[o].x);
            acc[o].y = fmaf(wr[o].y, dv, acc[o].y);
        }
    }

    size_t obase = ((size_t)b*64 + half*32) * (H3*W3) + (size_t)oh*W3 + ow;
    #pragma unroll
    for (int o = 0; o < 16; o++) {
        float vx = acc[o].x, vy = acc[o].y;
        out[obase + (size_t)(2*o  )*(H3*W3)] = vx > 0.f ? vx : (__expf(vx) - 1.f);
        out[obase + (size_t)(2*o+1)*(H3*W3)] = vy > 0.f ? vy : (__expf(vy) - 1.f);
    }
}

// ---------------- K4: attention pool + MLP + GRU head -----------------------
__global__ __launch_bounds__(1024) void k_head(
    const float* __restrict__ f3,
    const float* __restrict__ attn_w, const float* __restrict__ attn_b,
    const float* __restrict__ mlp1_w, const float* __restrict__ mlp1_b,
    const float* __restrict__ mlp2_w, const float* __restrict__ mlp2_b,
    const float* __restrict__ w_ih, const float* __restrict__ b_ih,
    const float* __restrict__ b_hh,
    const float* __restrict__ fc_w, const float* __restrict__ fc_b,
    float* __restrict__ out)
{
    const int N  = H3 * W3;   // 4800
    const int N4 = N / 4;     // 1200
    __shared__ float s_w[H3 * W3];
    __shared__ float s_attn[64];
    __shared__ float s_redm[16];
    __shared__ float s_reds[16];
    __shared__ float s_inv[1];
    __shared__ float s_pooled[64];
    __shared__ float s_h1[32];
    __shared__ float s_om[3];
    __shared__ float s_h[32];

    int t = threadIdx.x, b = blockIdx.x;
    int lane = t & 63, wid = t >> 6;   // 16 waves
    if (t < 64) s_attn[t] = attn_w[t];
    __syncthreads();

    const float4* fb4 = (const float4*)(f3 + (size_t)b * F3_PB);
    float ab = attn_b[0];

    float lmax = -1e30f;
    for (int n4 = t; n4 < N4; n4 += 1024) {
        float4 l = make_float4(ab, ab, ab, ab);
        #pragma unroll 8
        for (int c = 0; c < 64; c++) {
            float4 v = fb4[c * N4 + n4];
            float a = s_attn[c];
            l.x = fmaf(a, v.x, l.x); l.y = fmaf(a, v.y, l.y);
            l.z = fmaf(a, v.z, l.z); l.w = fmaf(a, v.w, l.w);
        }
        ((float4*)s_w)[n4] = l;
        lmax = fmaxf(lmax, fmaxf(fmaxf(l.x, l.y), fmaxf(l.z, l.w)));
    }
    #pragma unroll
    for (int off = 32; off; off >>= 1) lmax = fmaxf(lmax, __shfl_down(lmax, off, 64));
    if (lane == 0) s_redm[wid] = lmax;
    __syncthreads();
    {
        float m = s_redm[0];
        #pragma unroll
        for (int i = 1; i < 16; i++) m = fmaxf(m, s_redm[i]);
        lmax = m;
    }

    float lsum = 0.f;
    for (int n = t; n < N; n += 1024) { float e = __expf(s_w[n] - lmax); s_w[n] = e; lsum += e; }
    #pragma unroll
    for (int off = 32; off; off >>= 1) lsum += __shfl_down(lsum, off, 64);
    if (lane == 0) s_reds[wid] = lsum;
    __syncthreads();
    if (t == 0) {
        float s = 0.f;
        #pragma unroll
        for (int i = 0; i < 16; i++) s += s_reds[i];
        s_inv[0] = 1.f / s;
    }
    __syncthreads();
    float invS = s_inv[0];

    const float4* sw4 = (const float4*)s_w;
    for (int c = wid; c < 64; c += 16) {
        float s = 0.f;
        for (int i = lane; i < N4; i += 64) {
            float4 v = fb4[c * N4 + i];
            float4 w = sw4[i];
            s = fmaf(v.x, w.x, s); s = fmaf(v.y, w.y, s);
            s = fmaf(v.z, w.z, s); s = fmaf(v.w, w.w, s);
        }
        #pragma unroll
        for (int off = 32; off; off >>= 1) s += __shfl_down(s, off, 64);
        if (lane == 0) s_pooled[c] = s * invS;
    }
    __syncthreads();

    if (t < 32) {
        float a = mlp1_b[t];
        #pragma unroll 8
        for (int c = 0; c < 64; c++) a = fmaf(mlp1_w[t*64 + c], s_pooled[c], a);
        s_h1[t] = a > 0.f ? a : (__expf(a) - 1.f);
    }
    __syncthreads();
    if (t < 3) {
        float a = mlp2_b[t];
        for (int j = 0; j < 32; j++) a = fmaf(mlp2_w[t*32 + j], s_h1[j], a);
        s_om[t] = a;
    }
    __syncthreads();
    if (t < 32) {
        float gr = b_ih[t], gz = b_ih[32 + t], gn = b_ih[64 + t];
        #pragma unroll
        for (int k = 0; k < 3; k++) {
            float ok = s_om[k];
            gr = fmaf(w_ih[t*3 + k],        ok, gr);
            gz = fmaf(w_ih[(32 + t)*3 + k], ok, gz);
            gn = fmaf(w_ih[(64 + t)*3 + k], ok, gn);
        }
        float hr = b_hh[t], hz = b_hh[32 + t], hn = b_hh[64 + t];
        float r = 1.f / (1.f + __expf(-(gr + hr)));
        float z = 1.f / (1.f + __expf(-(gz + hz)));
        float nn = tanhf(gn + r * hn);
        s_h[t] = (1.f - z) * nn;
    }
    __syncthreads();
    if (t < 3) {
        float dl = fc_b[t];
        for (int j = 0; j < 32; j++) dl = fmaf(fc_w[t*32 + j], s_h[j], dl);
        out[b*3 + t] = s_om[t] + dl;
    }
}

// ---------------- host ----------------
extern "C" void kernel_launch(void* const* d_in, const int* in_sizes, int n_in,
                              void* d_out, int out_size, void* d_ws, size_t ws_size,
                              hipStream_t stream)
{
    const float* flow = (const float*)d_in[0];
    float* wb = (float*)d_ws;

    // layout: [wbuf][f2 all 32 batches][f3 all 32 batches] = 196.7 MB (ws >= 275 MB)
    float* f2 = (float*)((char*)d_ws + WBUF_BYTES);
    float* f3 = f2 + (size_t)32 * F2_PB;

    k_cvt<<<1, 256, 0, stream>>>(
        (const float*)d_in[2], (const float*)d_in[5], (const float*)d_in[8], wb);

    // fused stage1+stage2: one thread per f2 pixel
    k_fuse12<<<(32*H2*W2)/256, 256, 0, stream>>>(
        flow, (const float*)d_in[1], (const float*)d_in[3],
        (const float*)d_in[4], (const float*)d_in[6], wb, f2);

    // stage3: thread = (f3 px, oc-half) -> 1200 blocks
    k_stage3<<<(32*H3*W3*2)/256, 256, 0, stream>>>(
        f2, (const float*)d_in[7], (const float*)d_in[9], wb, f3);

    k_head<<<32, 1024, 0, stream>>>(f3,
        (const float*)d_in[10], (const float*)d_in[11],
        (const float*)d_in[12], (const float*)d_in[13],
        (const float*)d_in[14], (const float*)d_in[15],
        (const float*)d_in[16], (const float*)d_in[18],
        (const float*)d_in[19], (const float*)d_in[20],
        (const float*)d_in[21], (float*)d_out);
}